// Round 9
// baseline (214.422 us; speedup 1.0000x reference)
//
#include <hip/hip_runtime.h>
#include <math.h>

#define NTOK 2048
#define HDIM 768
#define NHEAD 12
#define NQ (NTOK * NHEAD)   // 24576 total query-vectors

typedef __attribute__((ext_vector_type(8))) short short8v;   // 8 bf16 (4 VGPR)
typedef __attribute__((ext_vector_type(4))) float float4v;   // MFMA acc

static __device__ __forceinline__ unsigned short f2bf(float x) {
    unsigned u = __float_as_uint(x);
    return (unsigned short)((u + 0x7fffu + ((u >> 16) & 1u)) >> 16);  // RNE
}
static __device__ __forceinline__ unsigned pk2(float a, float b) {   // [lo=a, hi=b]
    unsigned r;
    asm("v_cvt_pk_bf16_f32 %0, %1, %2" : "=v"(r) : "v"(a), "v"(b));
    return r;
}
static __device__ __forceinline__ void gload_lds16(const void* g, void* lds_uniform) {
    __builtin_amdgcn_global_load_lds(
        (const __attribute__((address_space(1))) void*)g,
        (__attribute__((address_space(3))) void*)lds_uniform, 16, 0, 0);
}

// ---------------------------------------------------------------------------
// Projection GEMM + fused cast + fused L2-norm.  (unchanged; passed, 2.4e-4)
// ---------------------------------------------------------------------------
__global__ __launch_bounds__(256) void projnorm_kernel(
    const float* __restrict__ hs, const float* __restrict__ Wq,
    const float* __restrict__ bq, const float* __restrict__ Wv,
    const float* __restrict__ bv, unsigned short* __restrict__ qbf,
    unsigned short* __restrict__ vT)
{
    constexpr int PITCH = 40;
    __shared__ unsigned short As[2][128 * PITCH];
    __shared__ unsigned short Bs[2][64 * PITCH];

    const bool isq = (blockIdx.z == 0);
    const float* W    = isq ? Wq : Wv;
    const float* bias = isq ? bq : bv;
    const int n0 = blockIdx.x * 64, m0 = blockIdx.y * 128;
    const int tid = threadIdx.x, lane = tid & 63, w = tid >> 6;

    const int arow = tid >> 1, acol = (tid & 1) * 16;   // A: 128 rows x 32 cols
    const int brow = tid >> 2, bcol = (tid & 3) * 8;    // B: 64 rows x 32 cols
    const float* ag = hs + (size_t)(m0 + arow) * HDIM + acol;
    const float* bg = W + (size_t)(n0 + brow) * HDIM + bcol;

    float4 ga[4], gb[2];
#define PLOAD(k0)                                                              \
    {                                                                          \
        _Pragma("unroll") for (int i = 0; i < 4; ++i)                          \
            ga[i] = *(const float4*)(ag + (k0) + i * 4);                       \
        _Pragma("unroll") for (int i = 0; i < 2; ++i)                          \
            gb[i] = *(const float4*)(bg + (k0) + i * 4);                       \
    }
#define PCVTW(b)                                                               \
    {                                                                          \
        uint4 u0 = {pk2(ga[0].x, ga[0].y), pk2(ga[0].z, ga[0].w),              \
                    pk2(ga[1].x, ga[1].y), pk2(ga[1].z, ga[1].w)};             \
        uint4 u1 = {pk2(ga[2].x, ga[2].y), pk2(ga[2].z, ga[2].w),              \
                    pk2(ga[3].x, ga[3].y), pk2(ga[3].z, ga[3].w)};             \
        *(uint4*)&As[b][arow * PITCH + acol]     = u0;                         \
        *(uint4*)&As[b][arow * PITCH + acol + 8] = u1;                         \
        uint4 u2 = {pk2(gb[0].x, gb[0].y), pk2(gb[0].z, gb[0].w),              \
                    pk2(gb[1].x, gb[1].y), pk2(gb[1].z, gb[1].w)};             \
        *(uint4*)&Bs[b][brow * PITCH + bcol] = u2;                             \
    }

    float4v acc[2][4];
    #pragma unroll
    for (int fr = 0; fr < 2; ++fr)
        #pragma unroll
        for (int fc = 0; fc < 4; ++fc) acc[fr][fc] = (float4v){0.f, 0.f, 0.f, 0.f};

    PLOAD(0);
    PCVTW(0);

    for (int ks = 0; ks < 24; ++ks) {
        const int b = ks & 1;
        if (ks < 23) PLOAD((ks + 1) * 32);
        __syncthreads();                       // LDS[b] visible to all waves
        short8v af[2], bf[4];
        #pragma unroll
        for (int fr = 0; fr < 2; ++fr)
            af[fr] = *(const short8v*)
                &As[b][(w * 32 + fr * 16 + (lane & 15)) * PITCH + ((lane >> 4) << 3)];
        #pragma unroll
        for (int fc = 0; fc < 4; ++fc)
            bf[fc] = *(const short8v*)
                &Bs[b][(fc * 16 + (lane & 15)) * PITCH + ((lane >> 4) << 3)];
        #pragma unroll
        for (int fr = 0; fr < 2; ++fr)
            #pragma unroll
            for (int fc = 0; fc < 4; ++fc)
                acc[fr][fc] = __builtin_amdgcn_mfma_f32_16x16x32_bf16(
                    af[fr], bf[fc], acc[fr][fc], 0, 0, 0);
        if (ks < 23) PCVTW(b ^ 1);             // safe: b^1 last read before barrier
    }
#undef PLOAD
#undef PCVTW

    float bcol4[4];
    #pragma unroll
    for (int fc = 0; fc < 4; ++fc) bcol4[fc] = bias[n0 + fc * 16 + (lane & 15)];

    if (isq) {
        #pragma unroll
        for (int fr = 0; fr < 2; ++fr)
            #pragma unroll
            for (int r = 0; r < 4; ++r) {
                float v[4];
                float ss = 0.f;
                #pragma unroll
                for (int fc = 0; fc < 4; ++fc) {
                    v[fc] = acc[fr][fc][r] + bcol4[fc];
                    ss = fmaf(v[fc], v[fc], ss);
                }
                ss += __shfl_xor(ss, 1);
                ss += __shfl_xor(ss, 2);
                ss += __shfl_xor(ss, 4);
                ss += __shfl_xor(ss, 8);
                float inv = 1.0f / fmaxf(sqrtf(ss), 1e-12f);
                int m = m0 + w * 32 + fr * 16 + ((lane >> 4) << 2) + r;
                #pragma unroll
                for (int fc = 0; fc < 4; ++fc)
                    qbf[(size_t)m * HDIM + n0 + fc * 16 + (lane & 15)] = f2bf(v[fc] * inv);
            }
    } else {
        #pragma unroll
        for (int fr = 0; fr < 2; ++fr)
            #pragma unroll
            for (int fc = 0; fc < 4; ++fc) {
                int f = n0 + fc * 16 + (lane & 15);
                int mtk = m0 + w * 32 + fr * 16 + ((lane >> 4) << 2);
                union { unsigned short u[4]; unsigned long long q; } pk;
                #pragma unroll
                for (int r = 0; r < 4; ++r) pk.u[r] = f2bf(acc[fr][fc][r] + bcol4[fc]);
                *(unsigned long long*)(vT + (size_t)f * NTOK + mtk) = pk.q;
            }
    }
}

// ---------------------------------------------------------------------------
// MFMA flash attention v4 (byte-identical to round 8: passed, attn 58.6us).
// ---------------------------------------------------------------------------
__global__ __launch_bounds__(128)
__attribute__((amdgpu_waves_per_eu(3, 3)))
void attn_kernel(
    const unsigned short* __restrict__ qbf,   // [24576][64] bf16 normalized
    const unsigned short* __restrict__ vT,    // [768][2048] bf16
    float* __restrict__ num0,                 // = d_out, ksp 0 numerator
    float* __restrict__ part1,                // ksp 1 numerator
    float* __restrict__ lbuf)                 // [2][24576] denominators
{
    __shared__ unsigned short Ksb[2][64 * 64];
    __shared__ unsigned short Pl[2][16 * 72];

    const int bid = blockIdx.x;
    const int swz = (bid & 7) * 192 + (bid >> 3);   // bijective: 1536 % 8 == 0
    const int h = swz >> 7, rem = swz & 127;
    const int qt = rem >> 1, ksp = rem & 1;
    const int tid = threadIdx.x, lane = tid & 63, w = tid >> 6;
    const int n0 = qt * 32;
    const int kbase0 = ksp * 1024;

    const unsigned short* kh = qbf + (size_t)h * NTOK * 64;
    const unsigned short* vh = vT + (size_t)h * 64 * NTOK;

    const unsigned short* qrow = kh + ((size_t)n0 + w * 16 + (lane & 15)) * 64;
    short8v qa[2];
    qa[0] = *(const short8v*)(qrow + ((lane >> 4) << 3));
    qa[1] = *(const short8v*)(qrow + 32 + ((lane >> 4) << 3));

#define STAGE_K(buf, m0v)                                                      \
    {                                                                          \
        _Pragma("unroll")                                                      \
        for (int i = 0; i < 4; ++i) {        /* 512 x 16B chunks, 128 thr */   \
            int ci = ((w * 4 + i) << 6) + lane;                                \
            int r = ci >> 3, c8 = (ci & 7) ^ (r & 7);                          \
            gload_lds16(kh + ((size_t)(m0v) + r) * 64 + (c8 << 3),             \
                        (char*)&Ksb[buf][0] + ((w * 4 + i) << 10));            \
        }                                                                      \
    }
    short8v vfA[8], vfB[8];
#define LOADV(VF, mb)                                                          \
    _Pragma("unroll")                                                          \
    for (int t = 0; t < 4; ++t)                                                \
        _Pragma("unroll")                                                      \
        for (int kk = 0; kk < 2; ++kk)                                         \
            VF[t * 2 + kk] = *(const short8v*)(                                \
                vh + (size_t)(t * 16 + (lane & 15)) * NTOK + (mb) +            \
                kk * 32 + ((lane >> 4) << 3));

    float4v acc[4];
    #pragma unroll
    for (int t = 0; t < 4; ++t) acc[t] = (float4v){0.f, 0.f, 0.f, 0.f};
    float lsum = 0.f;

#define TILE_BODY(MT, KB, VFC, VFN, LAST)                                      \
    {                                                                          \
        if (!(LAST)) {                                                         \
            STAGE_K((KB) ^ 1, kbase0 + ((MT) + 1) * 64);                       \
            LOADV(VFN, kbase0 + ((MT) + 1) * 64);                              \
            __builtin_amdgcn_sched_barrier(0);   /* pin issue point */         \
        }                                                                      \
        float4v St[4];                                                         \
        __builtin_amdgcn_s_setprio(1);                                         \
        _Pragma("unroll")                                                      \
        for (int t = 0; t < 4; ++t) {                                          \
            St[t] = (float4v){0.f, 0.f, 0.f, 0.f};                             \
            _Pragma("unroll")                                                  \
            for (int kk = 0; kk < 2; ++kk) {                                   \
                int row = (lane & 15) + (t << 4);                              \
                int off = ((row << 7) + (kk << 6) + ((lane >> 4) << 4)) ^      \
                          ((row & 7) << 4);                                    \
                short8v kf = *(const short8v*)((const char*)&Ksb[KB][0] + off);\
                St[t] = __builtin_amdgcn_mfma_f32_16x16x32_bf16(               \
                    kf, qa[kk], St[t], 0, 0, 0);                               \
            }                                                                  \
        }                                                                      \
        __builtin_amdgcn_s_setprio(0);                                         \
        float p[4][4];                                                         \
        float ls = 0.f;                                                        \
        _Pragma("unroll")                                                      \
        for (int t = 0; t < 4; ++t)                                            \
            _Pragma("unroll")                                                  \
            for (int r = 0; r < 4; ++r) {                                      \
                p[t][r] = __expf(St[t][r] * 0.25f);                            \
                ls += p[t][r];                                                 \
            }                                                                  \
        ls += __shfl_xor(ls, 16);                                              \
        ls += __shfl_xor(ls, 32);                                              \
        lsum += ls;                                                            \
        _Pragma("unroll")                                                      \
        for (int t = 0; t < 4; ++t) {                                          \
            unsigned w0 = pk2(p[t][0], p[t][1]);                               \
            unsigned w1 = pk2(p[t][2], p[t][3]);                               \
            unsigned long long q64 =                                           \
                (unsigned long long)w0 | ((unsigned long long)w1 << 32);       \
            *(unsigned long long*)(&Pl[w][(lane & 15) * 72 + t * 16 +          \
                                          ((lane >> 4) << 2)]) = q64;          \
        }                                                                      \
        asm volatile("s_waitcnt lgkmcnt(0)" ::: "memory");                     \
        __builtin_amdgcn_sched_barrier(0);                                     \
        short8v pf[2];                                                         \
        _Pragma("unroll")                                                      \
        for (int kk = 0; kk < 2; ++kk)                                         \
            pf[kk] = *(const short8v*)(&Pl[w][(lane & 15) * 72 + kk * 32 +     \
                                              ((lane >> 4) << 3)]);            \
        __builtin_amdgcn_s_setprio(1);                                         \
        _Pragma("unroll")                                                      \
        for (int t = 0; t < 4; ++t) {                                          \
            acc[t] = __builtin_amdgcn_mfma_f32_16x16x32_bf16(                  \
                pf[0], VFC[t * 2 + 0], acc[t], 0, 0, 0);                       \
            acc[t] = __builtin_amdgcn_mfma_f32_16x16x32_bf16(                  \
                pf[1], VFC[t * 2 + 1], acc[t], 0, 0, 0);                       \
        }                                                                      \
        __builtin_amdgcn_s_setprio(0);                                         \
        if (!(LAST)) {                                                         \
            asm volatile("s_waitcnt vmcnt(8)" ::: "memory"); /* K-DMA only */  \
            __builtin_amdgcn_s_barrier();        /* V rides across */          \
            __builtin_amdgcn_sched_barrier(0);                                 \
        }                                                                      \
    }

    STAGE_K(0, kbase0);
    LOADV(vfA, kbase0);
    __syncthreads();                        // prologue: full drain, all ready

    for (int it = 0; it < 8; ++it) {
        TILE_BODY(2 * it,     0, vfA, vfB, false);
        if (it < 7) {
            TILE_BODY(2 * it + 1, 1, vfB, vfA, false);
        } else {
            TILE_BODY(2 * it + 1, 1, vfB, vfA, true);
        }
    }
#undef TILE_BODY

    float* nout = ksp ? part1 : num0;
    #pragma unroll
    for (int r = 0; r < 4; ++r) {
        int n = n0 + w * 16 + ((lane >> 4) << 2) + r;
        #pragma unroll
        for (int t = 0; t < 4; ++t)
            nout[((size_t)h * NTOK + n) * 64 + t * 16 + (lane & 15)] = acc[t][r];
    }
    if (lane < 16)
        lbuf[ksp * NQ + h * NTOK + n0 + w * 16 + lane] = lsum;
#undef STAGE_K
#undef LOADV
}

// ---------------------------------------------------------------------------
// out = (num0 + part1) / (l0 + l1), float4-vectorized.  393216 float4s.
// ---------------------------------------------------------------------------
__global__ __launch_bounds__(256) void combine_kernel(
    float* __restrict__ out, const float* __restrict__ part1,
    const float* __restrict__ lbuf)
{
    int gid = blockIdx.x * 256 + threadIdx.x;
    float4 a = ((const float4*)out)[gid];
    float4 b = ((const float4*)part1)[gid];
    int row = gid >> 4;
    float inv = 1.0f / (lbuf[row] + lbuf[NQ + row]);
    float4 o;
    o.x = (a.x + b.x) * inv; o.y = (a.y + b.y) * inv;
    o.z = (a.z + b.z) * inv; o.w = (a.w + b.w) * inv;
    ((float4*)out)[gid] = o;
}

// ---------------------------------------------------------------------------
// PROBE A: K-path only (K-DMA dbuf + QK^T MFMA + exp + lsum).  No V, no P-LDS,
// no PV.  Writes lsum to dead scratch (lbuf region, post-combine).  Ablation
// probe per mistake-#8 discipline — measures the K/QK/softmax phase alone.
// ---------------------------------------------------------------------------
__global__ __launch_bounds__(128)
__attribute__((amdgpu_waves_per_eu(3, 3)))
void probe_qk_kernel(const unsigned short* __restrict__ qbf,
                     float* __restrict__ scratch)
{
    __shared__ unsigned short Ksb[2][64 * 64];

    const int bid = blockIdx.x;
    const int swz = (bid & 7) * 192 + (bid >> 3);
    const int h = swz >> 7, rem = swz & 127;
    const int qt = rem >> 1, ksp = rem & 1;
    const int tid = threadIdx.x, lane = tid & 63, w = tid >> 6;
    const int n0 = qt * 32;
    const int kbase0 = ksp * 1024;

    const unsigned short* kh = qbf + (size_t)h * NTOK * 64;
    const unsigned short* qrow = kh + ((size_t)n0 + w * 16 + (lane & 15)) * 64;
    short8v qa[2];
    qa[0] = *(const short8v*)(qrow + ((lane >> 4) << 3));
    qa[1] = *(const short8v*)(qrow + 32 + ((lane >> 4) << 3));

#define PQ_STAGE(buf, m0v)                                                     \
    {                                                                          \
        _Pragma("unroll")                                                      \
        for (int i = 0; i < 4; ++i) {                                          \
            int ci = ((w * 4 + i) << 6) + lane;                                \
            int r = ci >> 3, c8 = (ci & 7) ^ (r & 7);                          \
            gload_lds16(kh + ((size_t)(m0v) + r) * 64 + (c8 << 3),             \
                        (char*)&Ksb[buf][0] + ((w * 4 + i) << 10));            \
        }                                                                      \
    }

    float lsum = 0.f;
    PQ_STAGE(0, kbase0);
    __syncthreads();

    for (int mt = 0; mt < 16; ++mt) {
        const int cur = mt & 1;
        if (mt < 15) PQ_STAGE(cur ^ 1, kbase0 + (mt + 1) * 64);
        float4v St[4];
        __builtin_amdgcn_s_setprio(1);
        #pragma unroll
        for (int t = 0; t < 4; ++t) {
            St[t] = (float4v){0.f, 0.f, 0.f, 0.f};
            #pragma unroll
            for (int kk = 0; kk < 2; ++kk) {
                int row = (lane & 15) + (t << 4);
                int off = ((row << 7) + (kk << 6) + ((lane >> 4) << 4)) ^
                          ((row & 7) << 4);
                short8v kf = *(const short8v*)((const char*)&Ksb[cur][0] + off);
                St[t] = __builtin_amdgcn_mfma_f32_16x16x32_bf16(
                    kf, qa[kk], St[t], 0, 0, 0);
            }
        }
        __builtin_amdgcn_s_setprio(0);
        float ls = 0.f;
        #pragma unroll
        for (int t = 0; t < 4; ++t)
            #pragma unroll
            for (int r = 0; r < 4; ++r)
                ls += __expf(St[t][r] * 0.25f);
        ls += __shfl_xor(ls, 16);
        ls += __shfl_xor(ls, 32);
        lsum += ls;
        if (mt < 15) {
            asm volatile("s_waitcnt vmcnt(0)" ::: "memory");   // drain K-DMA
            __builtin_amdgcn_s_barrier();
            __builtin_amdgcn_sched_barrier(0);
        }
    }
#undef PQ_STAGE
    if (lane < 16)
        scratch[(size_t)bid * 32 + w * 16 + lane] = lsum;   // keeps all St live
}

// ---------------------------------------------------------------------------
// PROBE B: V-path only (V reg dbuf + PV MFMA with constant P).  No K, no LDS,
// no exp, no barriers.  Writes acc checksum to dead scratch (part1 region).
// ---------------------------------------------------------------------------
__global__ __launch_bounds__(128)
__attribute__((amdgpu_waves_per_eu(3, 3)))
void probe_pv_kernel(const unsigned short* __restrict__ vT,
                     float* __restrict__ scratch)
{
    const int bid = blockIdx.x;
    const int swz = (bid & 7) * 192 + (bid >> 3);
    const int h = swz >> 7, rem = swz & 127;
    const int ksp = rem & 1;
    const int tid = threadIdx.x, lane = tid & 63;
    const int kbase0 = ksp * 1024;
    const unsigned short* vh = vT + (size_t)h * 64 * NTOK;

    short8v pf;
    #pragma unroll
    for (int j = 0; j < 8; ++j) pf[j] = (short)0x3F80;   // bf16 1.0

    short8v vfA[8], vfB[8];
#define PV_LOADV(VF, mb)                                                       \
    _Pragma("unroll")                                                          \
    for (int t = 0; t < 4; ++t)                                                \
        _Pragma("unroll")                                                      \
        for (int kk = 0; kk < 2; ++kk)                                         \
            VF[t * 2 + kk] = *(const short8v*)(                                \
                vh + (size_t)(t * 16 + (lane & 15)) * NTOK + (mb) +            \
                kk * 32 + ((lane >> 4) << 3));

    float4v acc[4];
    #pragma unroll
    for (int t = 0; t < 4; ++t) acc[t] = (float4v){0.f, 0.f, 0.f, 0.f};

#define PV_TILE(MT, VFC, VFN, LAST)                                            \
    {                                                                          \
        if (!(LAST)) {                                                         \
            PV_LOADV(VFN, kbase0 + ((MT) + 1) * 64);                           \
            __builtin_amdgcn_sched_barrier(0);                                 \
        }                                                                      \
        __builtin_amdgcn_s_setprio(1);                                         \
        _Pragma("unroll")                                                      \
        for (int t = 0; t < 4; ++t) {                                          \
            acc[t] = __builtin_amdgcn_mfma_f32_16x16x32_bf16(                  \
                pf, VFC[t * 2 + 0], acc[t], 0, 0, 0);                          \
            acc[t] = __builtin_amdgcn_mfma_f32_16x16x32_bf16(                  \
                pf, VFC[t * 2 + 1], acc[t], 0, 0, 0);                          \
        }                                                                      \
        __builtin_amdgcn_s_setprio(0);                                         \
    }

    PV_LOADV(vfA, kbase0);
    for (int it = 0; it < 8; ++it) {
        PV_TILE(2 * it,     vfA, vfB, false);
        if (it < 7) {
            PV_TILE(2 * it + 1, vfB, vfA, false);
        } else {
            PV_TILE(2 * it + 1, vfB, vfA, true);
        }
    }
#undef PV_TILE
#undef PV_LOADV

    float4 o;   // checksum keeps every acc element live (no DCE, rule #17)
    o.x = acc[0][0] + acc[1][0] + acc[2][0] + acc[3][0];
    o.y = acc[0][1] + acc[1][1] + acc[2][1] + acc[3][1];
    o.z = acc[0][2] + acc[1][2] + acc[2][2] + acc[3][2];
    o.w = acc[0][3] + acc[1][3] + acc[2][3] + acc[3][3];
    ((float4*)scratch)[(size_t)bid * 128 + tid] = o;
}

// ---------------------------------------------------------------------------
extern "C" void kernel_launch(void* const* d_in, const int* in_sizes, int n_in,
                              void* d_out, int out_size, void* d_ws, size_t ws_size,
                              hipStream_t stream)
{
    const float* hs = (const float*)d_in[0];
    // d_in[1] = g, d_in[2] = attention_mask: feed only dead code -> unused.
    const float* Wq = (const float*)d_in[3];
    const float* bq = (const float*)d_in[4];
    const float* Wv = (const float*)d_in[5];
    const float* bv = (const float*)d_in[6];
    float* out = (float*)d_out;

    unsigned short* qbf   = (unsigned short*)d_ws;            // [2048*768] bf16
    unsigned short* vT    = qbf + (size_t)NTOK * HDIM;        // [768*2048] bf16
    float*          part1 = (float*)(vT + (size_t)HDIM * NTOK);   // [24576*64] f32
    float*          lbuf  = part1 + (size_t)NQ * 64;          // [2*24576] f32

    projnorm_kernel<<<dim3(12, 16, 2), 256, 0, stream>>>(
        hs, Wq, bq, Wv, bv, qbf, vT);
    attn_kernel<<<dim3(1536), 128, 0, stream>>>(qbf, vT, out, part1, lbuf);
    combine_kernel<<<dim3(1536), 256, 0, stream>>>(out, part1, lbuf);

    // Ablation probes: run AFTER combine; write only to regions dead after
    // combine (lbuf / part1).  Cannot affect d_out; purely diagnostic.
    probe_qk_kernel<<<dim3(1536), 128, 0, stream>>>(qbf, lbuf);
    probe_pv_kernel<<<dim3(1536), 128, 0, stream>>>(vT, part1);
}

// Round 10
// 186.217 us; speedup vs baseline: 1.1515x; 1.1515x over previous
//
#include <hip/hip_runtime.h>
#include <math.h>

#define NTOK 2048
#define HDIM 768
#define NHEAD 12
#define NQ (NTOK * NHEAD)   // 24576 total query-vectors

typedef __attribute__((ext_vector_type(8))) short short8v;   // 8 bf16 (4 VGPR)
typedef __attribute__((ext_vector_type(4))) float float4v;   // MFMA acc

static __device__ __forceinline__ unsigned short f2bf(float x) {
    unsigned u = __float_as_uint(x);
    return (unsigned short)((u + 0x7fffu + ((u >> 16) & 1u)) >> 16);  // RNE
}
static __device__ __forceinline__ unsigned pk2(float a, float b) {   // [lo=a, hi=b]
    unsigned r;
    asm("v_cvt_pk_bf16_f32 %0, %1, %2" : "=v"(r) : "v"(a), "v"(b));
    return r;
}

// ---------------------------------------------------------------------------
// Projection GEMM + fused cast + fused L2-norm.  (unchanged; passed, 2.4e-4)
// ---------------------------------------------------------------------------
__global__ __launch_bounds__(256) void projnorm_kernel(
    const float* __restrict__ hs, const float* __restrict__ Wq,
    const float* __restrict__ bq, const float* __restrict__ Wv,
    const float* __restrict__ bv, unsigned short* __restrict__ qbf,
    unsigned short* __restrict__ vT)
{
    constexpr int PITCH = 40;
    __shared__ unsigned short As[2][128 * PITCH];
    __shared__ unsigned short Bs[2][64 * PITCH];

    const bool isq = (blockIdx.z == 0);
    const float* W    = isq ? Wq : Wv;
    const float* bias = isq ? bq : bv;
    const int n0 = blockIdx.x * 64, m0 = blockIdx.y * 128;
    const int tid = threadIdx.x, lane = tid & 63, w = tid >> 6;

    const int arow = tid >> 1, acol = (tid & 1) * 16;   // A: 128 rows x 32 cols
    const int brow = tid >> 2, bcol = (tid & 3) * 8;    // B: 64 rows x 32 cols
    const float* ag = hs + (size_t)(m0 + arow) * HDIM + acol;
    const float* bg = W + (size_t)(n0 + brow) * HDIM + bcol;

    float4 ga[4], gb[2];
#define PLOAD(k0)                                                              \
    {                                                                          \
        _Pragma("unroll") for (int i = 0; i < 4; ++i)                          \
            ga[i] = *(const float4*)(ag + (k0) + i * 4);                       \
        _Pragma("unroll") for (int i = 0; i < 2; ++i)                          \
            gb[i] = *(const float4*)(bg + (k0) + i * 4);                       \
    }
#define PCVTW(b)                                                               \
    {                                                                          \
        uint4 u0 = {pk2(ga[0].x, ga[0].y), pk2(ga[0].z, ga[0].w),              \
                    pk2(ga[1].x, ga[1].y), pk2(ga[1].z, ga[1].w)};             \
        uint4 u1 = {pk2(ga[2].x, ga[2].y), pk2(ga[2].z, ga[2].w),              \
                    pk2(ga[3].x, ga[3].y), pk2(ga[3].z, ga[3].w)};             \
        *(uint4*)&As[b][arow * PITCH + acol]     = u0;                         \
        *(uint4*)&As[b][arow * PITCH + acol + 8] = u1;                         \
        uint4 u2 = {pk2(gb[0].x, gb[0].y), pk2(gb[0].z, gb[0].w),              \
                    pk2(gb[1].x, gb[1].y), pk2(gb[1].z, gb[1].w)};             \
        *(uint4*)&Bs[b][brow * PITCH + bcol] = u2;                             \
    }

    float4v acc[2][4];
    #pragma unroll
    for (int fr = 0; fr < 2; ++fr)
        #pragma unroll
        for (int fc = 0; fc < 4; ++fc) acc[fr][fc] = (float4v){0.f, 0.f, 0.f, 0.f};

    PLOAD(0);
    PCVTW(0);

    for (int ks = 0; ks < 24; ++ks) {
        const int b = ks & 1;
        if (ks < 23) PLOAD((ks + 1) * 32);
        __syncthreads();                       // LDS[b] visible to all waves
        short8v af[2], bf[4];
        #pragma unroll
        for (int fr = 0; fr < 2; ++fr)
            af[fr] = *(const short8v*)
                &As[b][(w * 32 + fr * 16 + (lane & 15)) * PITCH + ((lane >> 4) << 3)];
        #pragma unroll
        for (int fc = 0; fc < 4; ++fc)
            bf[fc] = *(const short8v*)
                &Bs[b][(fc * 16 + (lane & 15)) * PITCH + ((lane >> 4) << 3)];
        #pragma unroll
        for (int fr = 0; fr < 2; ++fr)
            #pragma unroll
            for (int fc = 0; fc < 4; ++fc)
                acc[fr][fc] = __builtin_amdgcn_mfma_f32_16x16x32_bf16(
                    af[fr], bf[fc], acc[fr][fc], 0, 0, 0);
        if (ks < 23) PCVTW(b ^ 1);             // safe: b^1 last read before barrier
    }
#undef PLOAD
#undef PCVTW

    float bcol4[4];
    #pragma unroll
    for (int fc = 0; fc < 4; ++fc) bcol4[fc] = bias[n0 + fc * 16 + (lane & 15)];

    if (isq) {
        #pragma unroll
        for (int fr = 0; fr < 2; ++fr)
            #pragma unroll
            for (int r = 0; r < 4; ++r) {
                float v[4];
                float ss = 0.f;
                #pragma unroll
                for (int fc = 0; fc < 4; ++fc) {
                    v[fc] = acc[fr][fc][r] + bcol4[fc];
                    ss = fmaf(v[fc], v[fc], ss);
                }
                ss += __shfl_xor(ss, 1);
                ss += __shfl_xor(ss, 2);
                ss += __shfl_xor(ss, 4);
                ss += __shfl_xor(ss, 8);
                float inv = 1.0f / fmaxf(sqrtf(ss), 1e-12f);
                int m = m0 + w * 32 + fr * 16 + ((lane >> 4) << 2) + r;
                #pragma unroll
                for (int fc = 0; fc < 4; ++fc)
                    qbf[(size_t)m * HDIM + n0 + fc * 16 + (lane & 15)] = f2bf(v[fc] * inv);
            }
    } else {
        #pragma unroll
        for (int fr = 0; fr < 2; ++fr)
            #pragma unroll
            for (int fc = 0; fc < 4; ++fc) {
                int f = n0 + fc * 16 + (lane & 15);
                int mtk = m0 + w * 32 + fr * 16 + ((lane >> 4) << 2);
                union { unsigned short u[4]; unsigned long long q; } pk;
                #pragma unroll
                for (int r = 0; r < 4; ++r) pk.u[r] = f2bf(acc[fr][fc][r] + bcol4[fc]);
                *(unsigned long long*)(vT + (size_t)f * NTOK + mtk) = pk.q;
            }
    }
}

// ---------------------------------------------------------------------------
// MFMA flash attention v5: probe_pv structure applied to the WHOLE kernel.
// K and V both direct L2 -> registers, explicitly double-buffered (kfA/kfB,
// vfA/vfB; all compile-time indices).  ZERO workgroup barriers, ZERO K/V LDS
// (r9 ablation: K-LDS-DMA + barrier path was ~55 of 59us; V-direct was ~5).
// Prefetch issued at tile top, pinned by sched_barrier(0); compiler's
// per-register vmcnt does the waiting.  amdgpu_waves_per_eu(2,2): 256-VGPR
// budget so the ~215-reg live set fits without collapsing the prefetch
// (r4/r6 failure mode).  P via wave-private LDS slab (pitch 72, lgkmcnt only).
// grid 1536 = 12h x 64qt x KSPLIT2, XCD-swizzled; block 128 = 2 indep waves.
// ---------------------------------------------------------------------------
__global__ __launch_bounds__(128)
__attribute__((amdgpu_waves_per_eu(2, 2)))
void attn_kernel(
    const unsigned short* __restrict__ qbf,   // [24576][64] bf16 normalized
    const unsigned short* __restrict__ vT,    // [768][2048] bf16
    float* __restrict__ num0,                 // = d_out, ksp 0 numerator
    float* __restrict__ part1,                // ksp 1 numerator
    float* __restrict__ lbuf)                 // [2][24576] denominators
{
    __shared__ unsigned short Pl[2][16 * 72];   // per-wave P slab only

    const int bid = blockIdx.x;
    const int swz = (bid & 7) * 192 + (bid >> 3);   // bijective: 1536 % 8 == 0
    const int h = swz >> 7, rem = swz & 127;
    const int qt = rem >> 1, ksp = rem & 1;
    const int tid = threadIdx.x, lane = tid & 63, w = tid >> 6;
    const int n0 = qt * 32;
    const int kbase0 = ksp * 1024;

    const unsigned short* kh = qbf + (size_t)h * NTOK * 64;
    const unsigned short* vh = vT + (size_t)h * 64 * NTOK;

    const unsigned short* qrow = kh + ((size_t)n0 + w * 16 + (lane & 15)) * 64;
    short8v qa[2];
    qa[0] = *(const short8v*)(qrow + ((lane >> 4) << 3));
    qa[1] = *(const short8v*)(qrow + 32 + ((lane >> 4) << 3));

    short8v kfA[8], kfB[8], vfA[8], vfB[8];
#define LOADK(KF, mb)                                                          \
    _Pragma("unroll")                                                          \
    for (int t = 0; t < 4; ++t)                                                \
        _Pragma("unroll")                                                      \
        for (int kk = 0; kk < 2; ++kk)                                         \
            KF[t * 2 + kk] = *(const short8v*)(                                \
                kh + ((size_t)((mb) + t * 16 + (lane & 15))) * 64 +            \
                kk * 32 + ((lane >> 4) << 3));
#define LOADV(VF, mb)                                                          \
    _Pragma("unroll")                                                          \
    for (int t = 0; t < 4; ++t)                                                \
        _Pragma("unroll")                                                      \
        for (int kk = 0; kk < 2; ++kk)                                         \
            VF[t * 2 + kk] = *(const short8v*)(                                \
                vh + (size_t)(t * 16 + (lane & 15)) * NTOK + (mb) +            \
                kk * 32 + ((lane >> 4) << 3));

    float4v acc[4];
    #pragma unroll
    for (int t = 0; t < 4; ++t) acc[t] = (float4v){0.f, 0.f, 0.f, 0.f};
    float lsum = 0.f;

// One tile.  KFC/VFC: regs for this tile; KFN/VFN: prefetch targets.
#define TILE_BODY(MT, KFC, KFN, VFC, VFN, LAST)                                \
    {                                                                          \
        if (!(LAST)) {                                                         \
            LOADK(KFN, kbase0 + ((MT) + 1) * 64);                              \
            LOADV(VFN, kbase0 + ((MT) + 1) * 64);                              \
            __builtin_amdgcn_sched_barrier(0);   /* pin issue point */         \
        }                                                                      \
        /* S^T = K.Q^T (keys t*16+(lane>>4)*4+r, query lane&15) */             \
        float4v St[4];                                                         \
        __builtin_amdgcn_s_setprio(1);                                         \
        _Pragma("unroll")                                                      \
        for (int t = 0; t < 4; ++t) {                                          \
            St[t] = (float4v){0.f, 0.f, 0.f, 0.f};                             \
            St[t] = __builtin_amdgcn_mfma_f32_16x16x32_bf16(                   \
                KFC[t * 2 + 0], qa[0], St[t], 0, 0, 0);                        \
            St[t] = __builtin_amdgcn_mfma_f32_16x16x32_bf16(                   \
                KFC[t * 2 + 1], qa[1], St[t], 0, 0, 0);                        \
        }                                                                      \
        __builtin_amdgcn_s_setprio(0);                                         \
        /* softmax numerators (scores in [-0.5,0]: no max pass) */             \
        float p[4][4];                                                         \
        float ls = 0.f;                                                        \
        _Pragma("unroll")                                                      \
        for (int t = 0; t < 4; ++t)                                            \
            _Pragma("unroll")                                                  \
            for (int r = 0; r < 4; ++r) {                                      \
                p[t][r] = __expf(St[t][r] * 0.25f);                            \
                ls += p[t][r];                                                 \
            }                                                                  \
        ls += __shfl_xor(ls, 16);                                              \
        ls += __shfl_xor(ls, 32);                                              \
        lsum += ls;                                                            \
        /* pack P -> wave-private LDS, reload as PV A-frags */                 \
        _Pragma("unroll")                                                      \
        for (int t = 0; t < 4; ++t) {                                          \
            unsigned w0 = pk2(p[t][0], p[t][1]);                               \
            unsigned w1 = pk2(p[t][2], p[t][3]);                               \
            unsigned long long q64 =                                           \
                (unsigned long long)w0 | ((unsigned long long)w1 << 32);       \
            *(unsigned long long*)(&Pl[w][(lane & 15) * 72 + t * 16 +          \
                                          ((lane >> 4) << 2)]) = q64;          \
        }                                                                      \
        asm volatile("s_waitcnt lgkmcnt(0)" ::: "memory");                     \
        __builtin_amdgcn_sched_barrier(0);                                     \
        short8v pf[2];                                                         \
        _Pragma("unroll")                                                      \
        for (int kk = 0; kk < 2; ++kk)                                         \
            pf[kk] = *(const short8v*)(&Pl[w][(lane & 15) * 72 + kk * 32 +     \
                                              ((lane >> 4) << 3)]);            \
        /* acc += P @ V */                                                     \
        __builtin_amdgcn_s_setprio(1);                                         \
        _Pragma("unroll")                                                      \
        for (int t = 0; t < 4; ++t) {                                          \
            acc[t] = __builtin_amdgcn_mfma_f32_16x16x32_bf16(                  \
                pf[0], VFC[t * 2 + 0], acc[t], 0, 0, 0);                       \
            acc[t] = __builtin_amdgcn_mfma_f32_16x16x32_bf16(                  \
                pf[1], VFC[t * 2 + 1], acc[t], 0, 0, 0);                       \
        }                                                                      \
        __builtin_amdgcn_s_setprio(0);                                         \
    }

    LOADK(kfA, kbase0);
    LOADV(vfA, kbase0);

    for (int it = 0; it < 8; ++it) {
        TILE_BODY(2 * it,     kfA, kfB, vfA, vfB, false);
        if (it < 7) {
            TILE_BODY(2 * it + 1, kfB, kfA, vfB, vfA, false);
        } else {
            TILE_BODY(2 * it + 1, kfB, kfA, vfB, vfA, true);
        }
    }
#undef TILE_BODY
#undef LOADK
#undef LOADV

    // ---- partial stores (numerator un-normalized, denominator separate)
    float* nout = ksp ? part1 : num0;
    #pragma unroll
    for (int r = 0; r < 4; ++r) {
        int n = n0 + w * 16 + ((lane >> 4) << 2) + r;
        #pragma unroll
        for (int t = 0; t < 4; ++t)
            nout[((size_t)h * NTOK + n) * 64 + t * 16 + (lane & 15)] = acc[t][r];
    }
    if (lane < 16)
        lbuf[ksp * NQ + h * NTOK + n0 + w * 16 + lane] = lsum;
}

// ---------------------------------------------------------------------------
// out = (num0 + part1) / (l0 + l1), float4-vectorized.  393216 float4s.
// ---------------------------------------------------------------------------
__global__ __launch_bounds__(256) void combine_kernel(
    float* __restrict__ out, const float* __restrict__ part1,
    const float* __restrict__ lbuf)
{
    int gid = blockIdx.x * 256 + threadIdx.x;
    float4 a = ((const float4*)out)[gid];
    float4 b = ((const float4*)part1)[gid];
    int row = gid >> 4;
    float inv = 1.0f / (lbuf[row] + lbuf[NQ + row]);
    float4 o;
    o.x = (a.x + b.x) * inv; o.y = (a.y + b.y) * inv;
    o.z = (a.z + b.z) * inv; o.w = (a.w + b.w) * inv;
    ((float4*)out)[gid] = o;
}

// ---------------------------------------------------------------------------
extern "C" void kernel_launch(void* const* d_in, const int* in_sizes, int n_in,
                              void* d_out, int out_size, void* d_ws, size_t ws_size,
                              hipStream_t stream)
{
    const float* hs = (const float*)d_in[0];
    // d_in[1] = g, d_in[2] = attention_mask: feed only dead code -> unused.
    const float* Wq = (const float*)d_in[3];
    const float* bq = (const float*)d_in[4];
    const float* Wv = (const float*)d_in[5];
    const float* bv = (const float*)d_in[6];
    float* out = (float*)d_out;

    unsigned short* qbf   = (unsigned short*)d_ws;            // [2048*768] bf16
    unsigned short* vT    = qbf + (size_t)NTOK * HDIM;        // [768*2048] bf16
    float*          part1 = (float*)(vT + (size_t)HDIM * NTOK);   // [24576*64] f32
    float*          lbuf  = part1 + (size_t)NQ * 64;          // [2*24576] f32

    projnorm_kernel<<<dim3(12, 16, 2), 256, 0, stream>>>(
        hs, Wq, bq, Wv, bv, qbf, vT);
    attn_kernel<<<dim3(1536), 128, 0, stream>>>(qbf, vT, out, part1, lbuf);
    combine_kernel<<<dim3(1536), 256, 0, stream>>>(out, part1, lbuf);
}